// Round 3
// baseline (455.725 us; speedup 1.0000x reference)
//
#include <hip/hip_runtime.h>

// FlowNet correlation: out[b, pp*9+oo, y, x] =
//   mean_c first[b,c,y,x] * second[b,c, y+pp-4, x+oo-4]   (zero outside)
//
// Round 3: 2 channels per barrier (64 syncs), prefetch distance = 1 super-step
// (s: global->reg->LDS, f: global->reg only, no LDS), 2 blocks/CU.

namespace {
constexpr int kPad = 4;
constexpr int kWin = 9;
constexpr int kB = 4, kC = 128, kH = 128, kW = 256;
constexpr int kTY = 2;                         // y-rows per block
constexpr int kWH = 128;                       // x-half width per block
constexpr int kXG = 16;                        // x-groups of 8 per half
constexpr int kPX = 8;                         // x-pixels per thread
constexpr int kThreads = kTY * kXG * kWin;     // 288
constexpr int kSRows = kTY + 2 * kPad;         // 10 second rows (halo)
constexpr int kRowC = (kWH + 2 * kPad) / 4;    // 34 float4 chunks per s-row
constexpr int kS4 = 38;                        // row stride in chunks
constexpr int kChBuf = kSRows * kS4 * 4;       // 1520 floats per channel buffer
constexpr int kNS = kSRows * kRowC;            // 340 chunks staged per channel
constexpr int kBlocks = kB * (kH / kTY) * 2;   // 512 -> 2 blocks/CU

__device__ __forceinline__ int swz(int c) { return c ^ (c >> 3); }
__device__ __forceinline__ float4 ldg4(const float* p) { return *(const float4*)p; }
}  // namespace

__global__ __launch_bounds__(kThreads, 3) void corr_kernel(
    const float* __restrict__ first,
    const float* __restrict__ second,
    float* __restrict__ out)
{
    __shared__ float lds[4 * kChBuf];   // 2 bufs x 2 channels = 24.3 KB

    const int tid  = threadIdx.x;
    const int p    = tid % kWin;
    const int xg   = (tid / kWin) % kXG;
    const int ysub = tid / (kWin * kXG);

    // XCD-aware bijective swizzle (512 = 8 x 64)
    int bid = blockIdx.x;
    bid = (bid & 7) * (kBlocks / 8) + (bid >> 3);
    const int b   = bid >> 7;
    const int rem = bid & 127;
    const int y0  = (rem >> 1) * kTY;
    const int wx0 = (rem & 1) * kWH;

    const size_t cstr  = (size_t)kH * kW;
    const size_t ibase = (size_t)b * kC * cstr;

    // --- s staging roles (second only; l0 valid for all 288 threads) ---
    const float* g0 = nullptr; int l0;
    const float* g1 = nullptr; int l1 = -1;
    {
        int r = tid / kRowC, c = tid - r * kRowC;
        int y = y0 - kPad + r, gx = wx0 - kPad + 4 * c;
        l0 = (r * kS4 + swz(c)) * 4;
        if (y >= 0 && y < kH && gx >= 0 && gx <= kW - 4)
            g0 = second + ibase + (size_t)y * kW + gx;
    }
    {
        int idx = tid + kThreads;
        if (idx < kNS) {
            int r = idx / kRowC, c = idx - r * kRowC;
            int y = y0 - kPad + r, gx = wx0 - kPad + 4 * c;
            l1 = (r * kS4 + swz(c)) * 4;
            if (y >= 0 && y < kH && gx >= 0 && gx <= kW - 4)
                g1 = second + ibase + (size_t)y * kW + gx;
        }
    }

    // --- f pointer (always in-bounds) ---
    const float* gf = first + ibase + (size_t)(y0 + ysub) * kW + (wx0 + 8 * xg);

    // --- loop-invariant LDS read offsets (floats, within one channel buffer) ---
    int offw[4];
#pragma unroll
    for (int k = 0; k < 4; ++k)
        offw[k] = ((ysub + p) * kS4 + swz(2 * xg + k)) * 4;

    float acc[kWin * kPX];
#pragma unroll
    for (int i = 0; i < kWin * kPX; ++i) acc[i] = 0.0f;

    auto compute = [&](int base, float4 flo, float4 fhi) {
        float w[16], f[8];
        float4 t;
        t = ldg4(&lds[base + offw[0]]); w[0]=t.x;  w[1]=t.y;  w[2]=t.z;  w[3]=t.w;
        t = ldg4(&lds[base + offw[1]]); w[4]=t.x;  w[5]=t.y;  w[6]=t.z;  w[7]=t.w;
        t = ldg4(&lds[base + offw[2]]); w[8]=t.x;  w[9]=t.y;  w[10]=t.z; w[11]=t.w;
        t = ldg4(&lds[base + offw[3]]); w[12]=t.x; w[13]=t.y; w[14]=t.z; w[15]=t.w;
        f[0]=flo.x; f[1]=flo.y; f[2]=flo.z; f[3]=flo.w;
        f[4]=fhi.x; f[5]=fhi.y; f[6]=fhi.z; f[7]=fhi.w;
#pragma unroll
        for (int o = 0; o < kWin; ++o)
#pragma unroll
            for (int j = 0; j < kPX; ++j)
                acc[o * kPX + j] = fmaf(f[j], w[j + o], acc[o * kPX + j]);
    };

    // --- prologue ---
    const float4 z = make_float4(0.f, 0.f, 0.f, 0.f);
    float4 s0c0 = z, s0c1 = z, s1c0 = z, s1c1 = z;        // held s chunks
    float4 f0lo, f0hi, f1lo, f1hi;                        // f for current pair

    if (g0) { s0c0 = ldg4(g0); s0c1 = ldg4(g0 + cstr); }
    if (g1) { s1c0 = ldg4(g1); s1c1 = ldg4(g1 + cstr); }
    *(float4*)&lds[0 * kChBuf + l0] = s0c0;
    *(float4*)&lds[1 * kChBuf + l0] = s0c1;
    if (l1 >= 0) {
        *(float4*)&lds[0 * kChBuf + l1] = s1c0;
        *(float4*)&lds[1 * kChBuf + l1] = s1c1;
    }
    // issue s for channels 2,3
    if (g0) { s0c0 = ldg4(g0 + 2 * cstr); s0c1 = ldg4(g0 + 3 * cstr); }
    if (g1) { s1c0 = ldg4(g1 + 2 * cstr); s1c1 = ldg4(g1 + 3 * cstr); }
    // issue f for channels 0,1
    f0lo = ldg4(gf);        f0hi = ldg4(gf + 4);
    f1lo = ldg4(gf + cstr); f1hi = ldg4(gf + cstr + 4);
    const float* gsp0 = g0 ? g0 + 4 * cstr : nullptr;     // next s issue (ch 4,5)
    const float* gsp1 = g1 ? g1 + 4 * cstr : nullptr;
    const float* gfp  = gf + 2 * cstr;                    // next f issue (ch 2,3)
    __syncthreads();

    // --- main loop: 64 super-steps of 2 channels ---
#pragma unroll 2
    for (int T = 0; T < kC / 2; ++T) {
        const int base = (T & 1) * (2 * kChBuf);
        compute(base,          f0lo, f0hi);
        compute(base + kChBuf, f1lo, f1hi);
        if (T < kC / 2 - 1) {
            // issue f for the next channel pair
            f0lo = ldg4(gfp);        f0hi = ldg4(gfp + 4);
            f1lo = ldg4(gfp + cstr); f1hi = ldg4(gfp + cstr + 4);
            gfp += 2 * cstr;
            // write held s (next pair) into the other buffer
            const int nb = ((T + 1) & 1) * (2 * kChBuf);
            *(float4*)&lds[nb + l0] = s0c0;
            *(float4*)&lds[nb + kChBuf + l0] = s0c1;
            if (l1 >= 0) {
                *(float4*)&lds[nb + l1] = s1c0;
                *(float4*)&lds[nb + kChBuf + l1] = s1c1;
            }
            // issue s for the pair after that
            if (T < kC / 2 - 2) {
                if (gsp0) { s0c0 = ldg4(gsp0); s0c1 = ldg4(gsp0 + cstr); gsp0 += 2 * cstr; }
                if (gsp1) { s1c0 = ldg4(gsp1); s1c1 = ldg4(gsp1 + cstr); gsp1 += 2 * cstr; }
            }
            __syncthreads();
        }
    }

    // --- epilogue: mean and store ---
    const float inv = 1.0f / (float)kC;
    const size_t obase = (size_t)b * (kWin * kWin) * cstr
                       + (size_t)(y0 + ysub) * kW + wx0 + 8 * xg;
#pragma unroll
    for (int o = 0; o < kWin; ++o) {
        const int d = p * kWin + o;
        float* op = out + obase + (size_t)d * cstr;
        float4 r0, r1;
        r0.x = acc[o * kPX + 0] * inv; r0.y = acc[o * kPX + 1] * inv;
        r0.z = acc[o * kPX + 2] * inv; r0.w = acc[o * kPX + 3] * inv;
        r1.x = acc[o * kPX + 4] * inv; r1.y = acc[o * kPX + 5] * inv;
        r1.z = acc[o * kPX + 6] * inv; r1.w = acc[o * kPX + 7] * inv;
        *(float4*)op = r0;
        *(float4*)(op + 4) = r1;
    }
}

extern "C" void kernel_launch(void* const* d_in, const int* in_sizes, int n_in,
                              void* d_out, int out_size, void* d_ws, size_t ws_size,
                              hipStream_t stream) {
    const float* first  = (const float*)d_in[0];
    const float* second = (const float*)d_in[1];
    float* out = (float*)d_out;
    dim3 grid(kBlocks);      // 512 blocks = 2 per CU
    dim3 block(kThreads);    // 288 threads
    hipLaunchKernelGGL(corr_kernel, grid, block, 0, stream, first, second, out);
}

// Round 4
// 152.199 us; speedup vs baseline: 2.9943x; 2.9943x over previous
//
#include <hip/hip_runtime.h>

// FlowNet correlation: out[b, pp*9+oo, y, x] =
//   mean_c first[b,c,y,x] * second[b,c, y+pp-4, x+oo-4]   (zero outside)
//
// Round 4 = round 2 (86.9 us) + ONE change: `first` bypasses LDS entirely
// (rolling distance-1 global->reg prefetch; 9x p-duplication hits L1).
// One channel per barrier, minimal live state, no min-waves launch bound
// (round 3's 2-channel super-step + held prefetch regs spilled: WRITE_SIZE
// 42->581 MB).

namespace {
constexpr int kPad = 4;
constexpr int kWin = 9;
constexpr int kB = 4, kC = 128, kH = 128, kW = 256;
constexpr int kTY = 2;                         // y-rows per block
constexpr int kWH = 128;                       // x-half width per block
constexpr int kXG = 16;                        // x-groups of 8 per half
constexpr int kPX = 8;                         // x-pixels per thread
constexpr int kThreads = kTY * kXG * kWin;     // 288
constexpr int kSRows = kTY + 2 * kPad;         // 10 second rows (halo)
constexpr int kRowC = (kWH + 2 * kPad) / 4;    // 34 float4 chunks per s-row
constexpr int kS4 = 38;                        // row stride in chunks
constexpr int kChBuf = kSRows * kS4 * 4;       // 1520 floats per buffer
constexpr int kNS = kSRows * kRowC;            // 340 chunks staged per channel
constexpr int kBlocks = kB * (kH / kTY) * 2;   // 512 -> 2 blocks/CU

__device__ __forceinline__ int swz(int c) { return c ^ (c >> 3); }
__device__ __forceinline__ float4 ldg4(const float* p) { return *(const float4*)p; }
}  // namespace

__global__ __launch_bounds__(kThreads) void corr_kernel(
    const float* __restrict__ first,
    const float* __restrict__ second,
    float* __restrict__ out)
{
    __shared__ float lds[2 * kChBuf];   // 12.2 KB (second only)

    const int tid  = threadIdx.x;
    const int p    = tid % kWin;
    const int xg   = (tid / kWin) % kXG;
    const int ysub = tid / (kWin * kXG);

    // XCD-aware bijective swizzle (512 = 8 x 64)
    int bid = blockIdx.x;
    bid = (bid & 7) * (kBlocks / 8) + (bid >> 3);
    const int b   = bid >> 7;
    const int rem = bid & 127;
    const int y0  = (rem >> 1) * kTY;
    const int wx0 = (rem & 1) * kWH;

    const size_t cstr  = (size_t)kH * kW;
    const size_t ibase = (size_t)b * kC * cstr;

    // --- s staging roles: up to 2 float4 per thread per channel ---
    const float* g0 = nullptr; int l0;
    const float* g1 = nullptr; int l1 = -1;
    {
        int r = tid / kRowC, c = tid - r * kRowC;
        int y = y0 - kPad + r, gx = wx0 - kPad + 4 * c;
        l0 = (r * kS4 + swz(c)) * 4;
        if (y >= 0 && y < kH && gx >= 0 && gx <= kW - 4)
            g0 = second + ibase + (size_t)y * kW + gx;
    }
    {
        int idx = tid + kThreads;
        if (idx < kNS) {
            int r = idx / kRowC, c = idx - r * kRowC;
            int y = y0 - kPad + r, gx = wx0 - kPad + 4 * c;
            l1 = (r * kS4 + swz(c)) * 4;
            if (y >= 0 && y < kH && gx >= 0 && gx <= kW - 4)
                g1 = second + ibase + (size_t)y * kW + gx;
        }
    }

    // --- f pointer (always in-bounds; 9 p-threads dup -> L1 broadcast) ---
    const float* gf = first + ibase + (size_t)(y0 + ysub) * kW + (wx0 + 8 * xg);

    // --- loop-invariant LDS read offsets ---
    int offw[4];
#pragma unroll
    for (int k = 0; k < 4; ++k)
        offw[k] = ((ysub + p) * kS4 + swz(2 * xg + k)) * 4;

    float acc[kWin * kPX];
#pragma unroll
    for (int i = 0; i < kWin * kPX; ++i) acc[i] = 0.0f;

    auto compute = [&](int base, float4 flo, float4 fhi) {
        float w[16], f[8];
        float4 t;
        t = ldg4(&lds[base + offw[0]]); w[0]=t.x;  w[1]=t.y;  w[2]=t.z;  w[3]=t.w;
        t = ldg4(&lds[base + offw[1]]); w[4]=t.x;  w[5]=t.y;  w[6]=t.z;  w[7]=t.w;
        t = ldg4(&lds[base + offw[2]]); w[8]=t.x;  w[9]=t.y;  w[10]=t.z; w[11]=t.w;
        t = ldg4(&lds[base + offw[3]]); w[12]=t.x; w[13]=t.y; w[14]=t.z; w[15]=t.w;
        f[0]=flo.x; f[1]=flo.y; f[2]=flo.z; f[3]=flo.w;
        f[4]=fhi.x; f[5]=fhi.y; f[6]=fhi.z; f[7]=fhi.w;
#pragma unroll
        for (int o = 0; o < kWin; ++o)
#pragma unroll
            for (int j = 0; j < kPX; ++j)
                acc[o * kPX + j] = fmaf(f[j], w[j + o], acc[o * kPX + j]);
    };

    // --- prologue: stage s(ch0), load f(ch0) ---
    float4 pf0 = make_float4(0.f, 0.f, 0.f, 0.f);
    float4 pf1 = make_float4(0.f, 0.f, 0.f, 0.f);
    if (g0) { pf0 = ldg4(g0); g0 += cstr; }
    if (g1) { pf1 = ldg4(g1); g1 += cstr; }
    *(float4*)&lds[l0] = pf0;
    if (l1 >= 0) *(float4*)&lds[l1] = pf1;
    float4 fclo = ldg4(gf), fchi = ldg4(gf + 4);
    const float* gfp = gf + cstr;
    __syncthreads();

    // --- main loop: prefetch s(c+1) & f(c+1), compute c, write s, barrier ---
    int cur = 0;
    for (int c = 0; c < kC - 1; ++c) {
        if (g0) { pf0 = ldg4(g0); g0 += cstr; }
        if (g1) { pf1 = ldg4(g1); g1 += cstr; }
        float4 fnlo = ldg4(gfp), fnhi = ldg4(gfp + 4);
        gfp += cstr;
        compute(cur * kChBuf, fclo, fchi);
        const int nb = (cur ^ 1) * kChBuf;
        *(float4*)&lds[nb + l0] = pf0;
        if (l1 >= 0) *(float4*)&lds[nb + l1] = pf1;
        __syncthreads();
        fclo = fnlo; fchi = fnhi;
        cur ^= 1;
    }
    compute(cur * kChBuf, fclo, fchi);

    // --- epilogue: mean and store ---
    const float inv = 1.0f / (float)kC;
    const size_t obase = (size_t)b * (kWin * kWin) * cstr
                       + (size_t)(y0 + ysub) * kW + wx0 + 8 * xg;
#pragma unroll
    for (int o = 0; o < kWin; ++o) {
        const int d = p * kWin + o;
        float* op = out + obase + (size_t)d * cstr;
        float4 r0, r1;
        r0.x = acc[o * kPX + 0] * inv; r0.y = acc[o * kPX + 1] * inv;
        r0.z = acc[o * kPX + 2] * inv; r0.w = acc[o * kPX + 3] * inv;
        r1.x = acc[o * kPX + 4] * inv; r1.y = acc[o * kPX + 5] * inv;
        r1.z = acc[o * kPX + 6] * inv; r1.w = acc[o * kPX + 7] * inv;
        *(float4*)op = r0;
        *(float4*)(op + 4) = r1;
    }
}

extern "C" void kernel_launch(void* const* d_in, const int* in_sizes, int n_in,
                              void* d_out, int out_size, void* d_ws, size_t ws_size,
                              hipStream_t stream) {
    const float* first  = (const float*)d_in[0];
    const float* second = (const float*)d_in[1];
    float* out = (float*)d_out;
    dim3 grid(kBlocks);      // 512 blocks = 2 per CU
    dim3 block(kThreads);    // 288 threads
    hipLaunchKernelGGL(corr_kernel, grid, block, 0, stream, first, second, out);
}

// Round 5
// 83.986 us; speedup vs baseline: 5.4262x; 1.8122x over previous
//
#include <hip/hip_runtime.h>

// FlowNet correlation: out[b, pp*9+oo, y, x] =
//   mean_c first[b,c,y,x] * second[b,c, y+pp-4, x+oo-4]   (zero outside)
//
// Round 5 = round 2 (86.9 us, best) with ONE change: thread mapping
// p=tid>>5 (was tid%9). Each 16-lane quarter-wave now reads ONE LDS row at
// consecutive chunks -> kills the multi-row bank conflicts (1.25e7 extra cyc
// ~= 20 us) that survived the round-2 column swizzle.

namespace {
constexpr int kPad = 4;
constexpr int kWin = 9;
constexpr int kB = 4, kC = 128, kH = 128, kW = 256;
constexpr int kTY = 2;                         // y-rows per block
constexpr int kWH = 128;                       // x-half width per block
constexpr int kXG = 16;                        // x-groups of 8 per half
constexpr int kPX = 8;                         // x-pixels per thread
constexpr int kThreads = kTY * kXG * kWin;     // 288
constexpr int kSRows = kTY + 2 * kPad;         // 10 second rows (halo)
constexpr int kRowC = (kWH + 2 * kPad) / 4;    // 34 float4 chunks per s-row
constexpr int kS4 = 38;                        // row stride in chunks
constexpr int kFRow = kSRows;                  // first rows stored as rows 10,11
constexpr int kBufC = (kSRows + kTY) * kS4;    // 456 chunks per buffer
constexpr int kBufF = kBufC * 4;               // 1824 floats per buffer
constexpr int kNS = kSRows * kRowC;            // 340 second chunks staged
constexpr int kNF = kTY * (kWH / 4);           // 64 first chunks staged
constexpr int kTot = kNS + kNF;                // 404
constexpr int kBlocks = kB * (kH / kTY) * 2;   // 512 -> 2 blocks/CU

__device__ __forceinline__ int swz(int c) { return c ^ (c >> 3); }
__device__ __forceinline__ float4 ldg4(const float* p) { return *(const float4*)p; }
}  // namespace

__global__ __launch_bounds__(kThreads) void corr_kernel(
    const float* __restrict__ first,
    const float* __restrict__ second,
    float* __restrict__ out)
{
    __shared__ float lds[2 * kBufF];   // 14.6 KB

    const int tid  = threadIdx.x;
    // p is the SLOW index: 32-lane groups share one p -> same-row LDS reads.
    const int p    = tid >> 5;                   // 0..8
    const int ysub = (tid >> 4) & 1;             // 0..1
    const int xg   = tid & 15;                   // 0..15

    // XCD-aware bijective swizzle (512 = 8 x 64)
    int bid = blockIdx.x;
    bid = (bid & 7) * (kBlocks / 8) + (bid >> 3);
    const int b   = bid >> 7;
    const int rem = bid & 127;
    const int y0  = (rem >> 1) * kTY;
    const int wx0 = (rem & 1) * kWH;

    const size_t cstr  = (size_t)kH * kW;
    const size_t ibase = (size_t)b * kC * cstr;

    // --- staging roles: up to 2 float4 per thread per channel (keyed by tid) ---
    const float* g0 = nullptr; int l0;
    const float* g1 = nullptr; int l1 = -1;
    {
        int r = tid / kRowC, c = tid - r * kRowC;
        int y = y0 - kPad + r, gx = wx0 - kPad + 4 * c;
        l0 = (r * kS4 + swz(c)) * 4;
        if (y >= 0 && y < kH && gx >= 0 && gx <= kW - 4)
            g0 = second + ibase + (size_t)y * kW + gx;
    }
    {
        int idx = tid + kThreads;
        if (idx < kNS) {
            int r = idx / kRowC, c = idx - r * kRowC;
            int y = y0 - kPad + r, gx = wx0 - kPad + 4 * c;
            l1 = (r * kS4 + swz(c)) * 4;
            if (y >= 0 && y < kH && gx >= 0 && gx <= kW - 4)
                g1 = second + ibase + (size_t)y * kW + gx;
        } else if (idx < kTot) {
            int i = idx - kNS;
            int ys = i >> 5, c = i & 31;
            l1 = ((kFRow + ys) * kS4 + swz(c)) * 4;
            g1 = first + ibase + (size_t)(y0 + ys) * kW + (wx0 + 4 * c);
        }
    }

    // --- loop-invariant LDS read offsets (floats) ---
    int offw[4], offf[2];
    {
        const int row = ysub + p;
#pragma unroll
        for (int k = 0; k < 4; ++k) offw[k] = (row * kS4 + swz(2 * xg + k)) * 4;
#pragma unroll
        for (int k = 0; k < 2; ++k) offf[k] = ((kFRow + ysub) * kS4 + swz(2 * xg + k)) * 4;
    }

    float acc[kWin * kPX];
#pragma unroll
    for (int i = 0; i < kWin * kPX; ++i) acc[i] = 0.0f;

    auto compute = [&](int cur) {
        const float* buf = &lds[cur * kBufF];
        float w[16], f[8];
        float4 t;
        t = ldg4(buf + offw[0]); w[0]=t.x;  w[1]=t.y;  w[2]=t.z;  w[3]=t.w;
        t = ldg4(buf + offw[1]); w[4]=t.x;  w[5]=t.y;  w[6]=t.z;  w[7]=t.w;
        t = ldg4(buf + offw[2]); w[8]=t.x;  w[9]=t.y;  w[10]=t.z; w[11]=t.w;
        t = ldg4(buf + offw[3]); w[12]=t.x; w[13]=t.y; w[14]=t.z; w[15]=t.w;
        t = ldg4(buf + offf[0]); f[0]=t.x;  f[1]=t.y;  f[2]=t.z;  f[3]=t.w;
        t = ldg4(buf + offf[1]); f[4]=t.x;  f[5]=t.y;  f[6]=t.z;  f[7]=t.w;
#pragma unroll
        for (int o = 0; o < kWin; ++o)
#pragma unroll
            for (int j = 0; j < kPX; ++j)
                acc[o * kPX + j] = fmaf(f[j], w[j + o], acc[o * kPX + j]);
    };

    // --- prologue: stage channel 0 ---
    float4 pf0 = make_float4(0.f, 0.f, 0.f, 0.f);
    float4 pf1 = make_float4(0.f, 0.f, 0.f, 0.f);
    if (g0) { pf0 = ldg4(g0); g0 += cstr; }
    if (g1) { pf1 = ldg4(g1); g1 += cstr; }
    *(float4*)&lds[l0] = pf0;
    if (l1 >= 0) *(float4*)&lds[l1] = pf1;
    __syncthreads();

    // --- main loop: prefetch c+1, compute c, write c+1, barrier ---
    int cur = 0;
    for (int c = 0; c < kC - 1; ++c) {
        if (g0) { pf0 = ldg4(g0); g0 += cstr; }
        if (g1) { pf1 = ldg4(g1); g1 += cstr; }
        compute(cur);
        const int nb = (cur ^ 1) * kBufF;
        *(float4*)&lds[nb + l0] = pf0;
        if (l1 >= 0) *(float4*)&lds[nb + l1] = pf1;
        __syncthreads();
        cur ^= 1;
    }
    compute(cur);

    // --- epilogue: mean and store ---
    const float inv = 1.0f / (float)kC;
    const size_t obase = (size_t)b * (kWin * kWin) * cstr
                       + (size_t)(y0 + ysub) * kW + wx0 + 8 * xg;
#pragma unroll
    for (int o = 0; o < kWin; ++o) {
        const int d = p * kWin + o;
        float* op = out + obase + (size_t)d * cstr;
        float4 r0, r1;
        r0.x = acc[o * kPX + 0] * inv; r0.y = acc[o * kPX + 1] * inv;
        r0.z = acc[o * kPX + 2] * inv; r0.w = acc[o * kPX + 3] * inv;
        r1.x = acc[o * kPX + 4] * inv; r1.y = acc[o * kPX + 5] * inv;
        r1.z = acc[o * kPX + 6] * inv; r1.w = acc[o * kPX + 7] * inv;
        *(float4*)op = r0;
        *(float4*)(op + 4) = r1;
    }
}

extern "C" void kernel_launch(void* const* d_in, const int* in_sizes, int n_in,
                              void* d_out, int out_size, void* d_ws, size_t ws_size,
                              hipStream_t stream) {
    const float* first  = (const float*)d_in[0];
    const float* second = (const float*)d_in[1];
    float* out = (float*)d_out;
    dim3 grid(kBlocks);      // 512 blocks = 2 per CU
    dim3 block(kThreads);    // 288 threads
    hipLaunchKernelGGL(corr_kernel, grid, block, 0, stream, first, second, out);
}

// Round 6
// 68.007 us; speedup vs baseline: 6.7012x; 1.2350x over previous
//
#include <hip/hip_runtime.h>

// FlowNet correlation via bf16 MFMA (gfx950).
// out[b, p*9+o, y, x] = (1/128) sum_c f[b,c,y,x] * s[b,c,y+p-4,x+o-4], zero-pad.
//
// Banded-GEMM: per (b,y,p) OUT[x,x'] = sum_c F[x,c] S[c,x'], keep |x'-x|<=4.
// Block = (b, 4y, 32x). 16 waves = (yslot 0..3) x (mn 0..3: M0N0,M0N1,M1N1,M1N2),
// N-tiles at x' base X0-8 + N*16. Each wave: 9 p-accumulators (16x16 tiles).
// K = 128 channels in 4 chunks of 32; both operands staged [x][c] bf16 in LDS
// (transpose during cvt), stride 40 entries -> conflict-free b128 frag reads.
// T14: global loads for chunk k+1 issued before compute(k), written after.

namespace {
constexpr int kC = 128, kH = 128, kW = 256;
constexpr int kWin = 9;
constexpr int kYB = 4, kXB = 32;
constexpr int kSR = kYB + 8;                      // 12 s-rows
constexpr int kSX = kXB + 16;                     // 48 s-cols (x' span)
constexpr int kCP = 40;                           // padded c-stride (entries)
constexpr int kKC = 32;                           // channels per chunk
constexpr int kNK = kC / kKC;                     // 4
constexpr int kSSz = kSR * kSX * kCP;             // 23040 entries
constexpr int kFSz = kYB * kXB * kCP;             // 5120
constexpr int kBufSz = kSSz + kFSz;               // 28160 entries = 56320 B
constexpr int kSU = kSR * (kSX / 4) * (kKC / 4);  // 1152 staging units
constexpr int kFU = kYB * (kXB / 4) * (kKC / 4);  // 256
constexpr int kTU = kSU + kFU;                    // 1408
constexpr int kThreads = 1024;
constexpr int kBlocks = 4 * (kH / kYB) * (kW / kXB);  // 1024
constexpr int kOS = 132;                          // OUT_lds per-d stride (words)
constexpr int kCStr = kH * kW;                    // 32768

typedef __attribute__((ext_vector_type(8))) short bf16x8;
typedef __attribute__((ext_vector_type(4))) float f32x4;

__device__ __forceinline__ unsigned short f2bf(float f) {
    unsigned u = __builtin_bit_cast(unsigned, f);
    return (unsigned short)((u + 0x7FFFu + ((u >> 16) & 1u)) >> 16);
}
}  // namespace

__global__ __launch_bounds__(kThreads) void corr_mfma(
    const float* __restrict__ first,
    const float* __restrict__ second,
    float* __restrict__ out)
{
    __shared__ __align__(16) unsigned short lds[kBufSz];   // 56.3 KB

    const int tid  = threadIdx.x;
    const int lane = tid & 63;
    const int wid  = tid >> 6;          // 0..15
    const int yslot = wid >> 2;         // 0..3
    const int mn    = wid & 3;          // 0:M0N0 1:M0N1 2:M1N1 3:M1N2

    // XCD-aware bijective swizzle (1024 = 8 x 128)
    int bid = blockIdx.x;
    bid = (bid & 7) * (kBlocks / 8) + (bid >> 3);
    const int b   = bid >> 8;
    const int rem = bid & 255;
    const int y0  = (rem >> 3) * kYB;
    const int X0  = (rem & 7) * kXB;

    // ---- staging roles: up to 2 transpose-units per thread ----
    // unit = (row, x-quad, c-quad): 4 float4 loads (c..c+3) -> 4 ds_write_b64
    const float* ug[2] = {nullptr, nullptr};
    int ul[2] = {-1, -1};
#pragma unroll
    for (int s = 0; s < 2; ++s) {
        int u = tid + s * kThreads;
        if (u >= kTU) break;
        if (u < kSU) {
            int row = u / 96, r2 = u % 96;
            int xq = r2 >> 3, cq = r2 & 7;
            int yg = y0 - 4 + row, xg = X0 - 8 + xq * 4;
            ul[s] = (row * kSX + xq * 4) * kCP + cq * 4;
            if (yg >= 0 && yg < kH && xg >= 0 && xg <= kW - 4)
                ug[s] = second + ((size_t)(b * kC + cq * 4) * kH + yg) * kW + xg;
        } else {
            int u2 = u - kSU;
            int row = u2 >> 6, r2 = u2 & 63;
            int xq = r2 >> 3, cq = r2 & 7;
            ul[s] = kSSz + (row * kXB + xq * 4) * kCP + cq * 4;
            ug[s] = first + ((size_t)(b * kC + cq * 4) * kH + (y0 + row)) * kW
                          + (X0 + xq * 4);
        }
    }

    float4 pv[2][4];
    auto issue = [&](int kc) {
#pragma unroll
        for (int s = 0; s < 2; ++s) {
            if (ul[s] < 0) continue;
            float4 z = make_float4(0.f, 0.f, 0.f, 0.f);
            pv[s][0] = z; pv[s][1] = z; pv[s][2] = z; pv[s][3] = z;
            if (ug[s]) {
                const float* g = ug[s] + (size_t)kc * kKC * kCStr;
                pv[s][0] = *(const float4*)g;
                pv[s][1] = *(const float4*)(g + kCStr);
                pv[s][2] = *(const float4*)(g + 2 * kCStr);
                pv[s][3] = *(const float4*)(g + 3 * kCStr);
            }
        }
    };
    auto write_lds = [&]() {
#pragma unroll
        for (int s = 0; s < 2; ++s) {
            if (ul[s] < 0) continue;
            unsigned short* d = &lds[ul[s]];
            uint2 w;
            w.x = f2bf(pv[s][0].x) | ((unsigned)f2bf(pv[s][1].x) << 16);
            w.y = f2bf(pv[s][2].x) | ((unsigned)f2bf(pv[s][3].x) << 16);
            *(uint2*)(d + 0 * kCP) = w;
            w.x = f2bf(pv[s][0].y) | ((unsigned)f2bf(pv[s][1].y) << 16);
            w.y = f2bf(pv[s][2].y) | ((unsigned)f2bf(pv[s][3].y) << 16);
            *(uint2*)(d + 1 * kCP) = w;
            w.x = f2bf(pv[s][0].z) | ((unsigned)f2bf(pv[s][1].z) << 16);
            w.y = f2bf(pv[s][2].z) | ((unsigned)f2bf(pv[s][3].z) << 16);
            *(uint2*)(d + 2 * kCP) = w;
            w.x = f2bf(pv[s][0].w) | ((unsigned)f2bf(pv[s][1].w) << 16);
            w.y = f2bf(pv[s][2].w) | ((unsigned)f2bf(pv[s][3].w) << 16);
            *(uint2*)(d + 3 * kCP) = w;
        }
    };

    // ---- compute-side fragment offsets (constant across k-chunks) ----
    const int l15 = lane & 15, lg = lane >> 4;
    const int Ms = mn >> 1, Ns = (mn + 1) >> 1;
    const int aoff = kSSz + (yslot * kXB + Ms * 16 + l15) * kCP + lg * 8;
    const int boff = (yslot * kSX + Ns * 16 + l15) * kCP + lg * 8;

    f32x4 acc[kWin];
    {
        f32x4 z = {0.f, 0.f, 0.f, 0.f};
#pragma unroll
        for (int p = 0; p < kWin; ++p) acc[p] = z;
    }

    // ---- K loop: issue(k+1) before compute(k), write after barrier (T14) ----
    issue(0);
    for (int kc = 0; kc < kNK; ++kc) {
        write_lds();
        __syncthreads();
        if (kc < kNK - 1) issue(kc + 1);
        bf16x8 a = *(const bf16x8*)&lds[aoff];
#pragma unroll
        for (int p = 0; p < kWin; ++p) {
            bf16x8 bb = *(const bf16x8*)&lds[boff + p * (kSX * kCP)];
            acc[p] = __builtin_amdgcn_mfma_f32_16x16x32_bf16(a, bb, acc[p], 0, 0, 0);
        }
        __syncthreads();
    }

    // ---- epilogue: band-extract into OUT_lds, then coalesced stores ----
    // D layout: col n = lane&15 (x' in N-tile), row m = 4*(lane>>4)+r (x in M-tile)
    float* outb = (float*)lds;
    const float inv = 1.0f / (float)kC;
    const int delta = (mn & 1) ? 12 : -4;      // (Xn - Xm) + 4
#pragma unroll
    for (int p = 0; p < kWin; ++p) {
#pragma unroll
        for (int r = 0; r < 4; ++r) {
            int m = (lg << 2) + r;
            int o = l15 - m + delta;
            if (o >= 0 && o < kWin) {
                int d = p * kWin + o;
                outb[d * kOS + yslot * kXB + Ms * 16 + m] = acc[p][r] * inv;
            }
        }
    }
    __syncthreads();

    const size_t ob = (size_t)b * (kWin * kWin) * kCStr;
    for (int i = tid; i < kWin * kWin * kYB * (kXB / 4); i += kThreads) {
        int d = i >> 5;                 // 32 float4 per d (4y x 8xq)
        int r2 = i & 31;
        int yy = r2 >> 3, xq = r2 & 7;
        float4 v = *(const float4*)&outb[d * kOS + yy * kXB + xq * 4];
        *(float4*)&out[ob + ((size_t)d * kH + (y0 + yy)) * kW + X0 + xq * 4] = v;
    }
}

extern "C" void kernel_launch(void* const* d_in, const int* in_sizes, int n_in,
                              void* d_out, int out_size, void* d_ws, size_t ws_size,
                              hipStream_t stream) {
    const float* first  = (const float*)d_in[0];
    const float* second = (const float*)d_in[1];
    float* out = (float*)d_out;
    dim3 grid(kBlocks);      // 1024 blocks
    dim3 block(kThreads);    // 1024 threads = 16 waves
    hipLaunchKernelGGL(corr_mfma, grid, block, 0, stream, first, second, out);
}